// Round 5
// baseline (2823.205 us; speedup 1.0000x reference)
//
#include <hip/hip_runtime.h>

typedef __attribute__((ext_vector_type(8))) short short8;   // 8 x bf16 (4 VGPRs)
typedef __attribute__((ext_vector_type(4))) float f32x4;
typedef __attribute__((ext_vector_type(2))) float f32x2;

#define NB 128
#define NT 256
#define NA 8
#define NH 1024
#define NG 3072   // 3*NH

__device__ __forceinline__ unsigned short f2bf(float f) {
    unsigned v;
    __builtin_memcpy(&v, &f, 4);
    v = v + 0x7fffu + ((v >> 16) & 1u);   // round-to-nearest-even
    return (unsigned short)(v >> 16);
}
__device__ __forceinline__ float sigm_f(float u)  { return 1.f / (1.f + __expf(-u)); }
// overflow-safe tanh
__device__ __forceinline__ float tanh_f(float u)  { return 1.f - 2.f / (1.f + __expf(2.f * u)); }

// ===========================================================================
// FAST PATH (MFMA) — needs ~84.4 MB ws
// ===========================================================================

// fp32 -> bf16 pack (weights)
__global__ __launch_bounds__(256) void wconv_kernel(
    const float* __restrict__ src, unsigned short* __restrict__ dst, int n)
{
    for (int i = (blockIdx.x * 256 + threadIdx.x) * 4; i < n; i += gridDim.x * 256 * 4) {
        float4 v = *(const float4*)(src + i);
        ushort4 o;
        o.x = f2bf(v.x); o.y = f2bf(v.y); o.z = f2bf(v.z); o.w = f2bf(v.w);
        *(ushort4*)(dst + i) = o;
    }
}

// x[b,t,h] = relu(actions[b,t,:]·fc_w[h,:] + fc_b[h]) -> bf16 into ws
__global__ __launch_bounds__(256) void xproj_bf16_kernel(
    const float* __restrict__ actions,   // [B,T,A] fp32
    const float* __restrict__ fc_w,      // [H,A]  fp32
    const float* __restrict__ fc_b,      // [H]    fp32
    unsigned short* __restrict__ xbf)    // [B,T,H] bf16 (ws)
{
    const int bt  = blockIdx.x;
    const int tid = threadIdx.x;

    const float* ap = actions + (size_t)bt * NA;
    float a[8];
#pragma unroll
    for (int i = 0; i < 8; ++i) a[i] = ap[i];

    const int h0 = tid * 4;
    unsigned short r[4];
#pragma unroll
    for (int j = 0; j < 4; ++j) {
        const float* wp = fc_w + (size_t)(h0 + j) * NA;
        float acc = fc_b[h0 + j];
#pragma unroll
        for (int i = 0; i < 8; ++i) acc += a[i] * wp[i];
        r[j] = f2bf(fmaxf(acc, 0.f));
    }
    ushort4 pk;
    pk.x = r[0]; pk.y = r[1]; pk.z = r[2]; pk.w = r[3];
    *(ushort4*)(xbf + (size_t)bt * NH + h0) = pk;
}

// ---------------------------------------------------------------------------
// Block tile: (bb 0..3 -> 32 batch rows) x (hc 0..63 -> 16 h outputs = 48
// gate rows). 4 waves k-split K=1024 into 256 each; partials reduced in LDS.
// MFMA 16x16x32 bf16.  A: lane holds A[m=lane&15][k=(lane>>4)*8+j].
//                      B: lane holds B[k=(lane>>4)*8+j][n=lane&15].
//                      D: lane reg i holds D[m=(lane>>4)*4+i][n=lane&15].
// ---------------------------------------------------------------------------

// ======================= persistent cooperative kernel =====================
// R1 lesson: acquire/release agent fences emit buffer_inv/wbl2 (L2 wipe).
// R2 lesson: single fetch_add counter barrier = same-address RMW serialization
//   at the LLC (64 adds + 63 pollers on one line ≈ 6 us/step idle).
// R3/R4: distributed epoch barrier — each block publishes its epoch to a
//   PRIVATE slot (plain sc1 store, no RMW); wave 0's 64 lanes poll the 64
//   slots with one coalesced 256B load + __all() ballot. Plus: bb-groups
//   confined to 2 XCDs via bid swizzle (x fetched 2x not 8x), and hB-load
//   latency hidden under the (independent) xq MFMA block.

__device__ __forceinline__ void bb_barrier(unsigned* slots, int mySlot, unsigned epoch) {
    __syncthreads();                 // every wave drains vmcnt: hB stores at LLC
    if (threadIdx.x < 64) {
        if (threadIdx.x == 0)
            __hip_atomic_store(slots + mySlot, epoch,
                               __ATOMIC_RELAXED, __HIP_MEMORY_SCOPE_AGENT);
        for (;;) {
            unsigned v = __hip_atomic_load(slots + (int)threadIdx.x,
                                           __ATOMIC_RELAXED, __HIP_MEMORY_SCOPE_AGENT);
            if (__all((int)(v >= epoch))) break;
            __builtin_amdgcn_s_sleep(1);
        }
    }
    __syncthreads();
    asm volatile("" ::: "memory");   // compile-time order pin (no HW cost)
}

__device__ __forceinline__ short8 ld_hB16(const unsigned short* p) {
    union { unsigned long long u[2]; short8 v; } r;
    r.u[0] = __hip_atomic_load((const unsigned long long*)p,
                               __ATOMIC_RELAXED, __HIP_MEMORY_SCOPE_AGENT);
    r.u[1] = __hip_atomic_load((const unsigned long long*)(p + 4),
                               __ATOMIC_RELAXED, __HIP_MEMORY_SCOPE_AGENT);
    return r.v;
}

__device__ __forceinline__ void st_hB2(unsigned short* p, unsigned short lo, unsigned short hi) {
    unsigned v = (unsigned)lo | ((unsigned)hi << 16);
    __hip_atomic_store((unsigned*)p, v, __ATOMIC_RELAXED, __HIP_MEMORY_SCOPE_AGENT);
}

__global__ __launch_bounds__(256, 1) void gru_persistent(
    float* __restrict__ out,                      // [B,T,H] fp32
    const unsigned short* __restrict__ xbf,       // [B,T,H] bf16
    const unsigned short* __restrict__ wih,      // [3H,H] bf16
    const unsigned short* __restrict__ whh,      // [3H,H] bf16
    const float* __restrict__ b_ih,
    const float* __restrict__ b_hh,
    const float* __restrict__ hidden0,            // [B,H] fp32
    unsigned short* __restrict__ hB,              // [2][B][H] bf16 (LLC-coherent)
    unsigned* __restrict__ slotbase)              // 4 groups x 64 epoch slots
{
    const int tid = threadIdx.x;
    const int kw = tid >> 6, lane = tid & 63, col = lane & 15, q = lane >> 4;
    // XCD-confining swizzle (empirically xcd = bid % 8): bb-group -> 2 XCDs.
    const int bid = (int)blockIdx.x;
    const int bb = (bid & 7) >> 1;
    const int hc = ((bid >> 3) << 1) | (bid & 1);
    const int koff = kw * 256 + q * 8;
    unsigned* slots = slotbase + bb * 64;

    __shared__ float hp_d[4][32][49];
    __shared__ float xq_d[4][32][49];

    // ---- step-invariant weight fragments -> registers (24+24 short8) ----
    short8 wf_hh[3][8], wf_ih[3][8];
#pragma unroll
    for (int g = 0; g < 3; ++g) {
        const unsigned short* Wh = whh + (size_t)(g * NH + hc * 16 + col) * NH + koff;
        const unsigned short* Wi = wih + (size_t)(g * NH + hc * 16 + col) * NH + koff;
#pragma unroll
        for (int s = 0; s < 8; ++s) {
            wf_hh[g][s] = *(const short8*)(Wh + s * 32);
            wf_ih[g][s] = *(const short8*)(Wi + s * 32);
        }
    }

    // ---- epilogue mapping + per-thread persistent state ----
    const int eb = tid >> 3, eh2 = (tid & 7) * 2, ebg = bb * 32 + eb;
    const int hg0 = hc * 16 + eh2;

    float bi_r[2][3], bh_r[2][3];
#pragma unroll
    for (int e = 0; e < 2; ++e)
#pragma unroll
        for (int g = 0; g < 3; ++g) {
            bi_r[e][g] = b_ih[g * NH + hg0 + e];
            bh_r[e][g] = b_hh[g * NH + hg0 + e];
        }

    const size_t xrow   = (size_t)(bb * 32 + col) * (NT * NH) + koff;
    const size_t xtile1 = (size_t)16 * NT * NH;

    // x A-fragment prefetch registers (slice currently needed by xq GEMM)
    short8 xa0[8], xa1[8];
    {
        const unsigned short* Ax = xbf + xrow;    // slice t=0
#pragma unroll
        for (int s = 0; s < 8; ++s) {
            xa0[s] = *(const short8*)(Ax + s * 32);
            xa1[s] = *(const short8*)(Ax + xtile1 + s * 32);
        }
    }

    float xq_r[2][3];   // xp[t] for this thread's 2 outputs (r,z,n)
    float hprev[2];     // h_t for this thread's 2 outputs

    // ---- init: xq(t=0) -> xq_r; h0 -> hprev + hB slot 0 ----
    {
        f32x4 xq[6];
#pragma unroll
        for (int i = 0; i < 6; ++i) xq[i] = (f32x4){0.f, 0.f, 0.f, 0.f};
#pragma unroll
        for (int s = 0; s < 8; ++s) {
            xq[0] = __builtin_amdgcn_mfma_f32_16x16x32_bf16(xa0[s], wf_ih[0][s], xq[0], 0, 0, 0);
            xq[1] = __builtin_amdgcn_mfma_f32_16x16x32_bf16(xa0[s], wf_ih[1][s], xq[1], 0, 0, 0);
            xq[2] = __builtin_amdgcn_mfma_f32_16x16x32_bf16(xa0[s], wf_ih[2][s], xq[2], 0, 0, 0);
            xq[3] = __builtin_amdgcn_mfma_f32_16x16x32_bf16(xa1[s], wf_ih[0][s], xq[3], 0, 0, 0);
            xq[4] = __builtin_amdgcn_mfma_f32_16x16x32_bf16(xa1[s], wf_ih[1][s], xq[4], 0, 0, 0);
            xq[5] = __builtin_amdgcn_mfma_f32_16x16x32_bf16(xa1[s], wf_ih[2][s], xq[5], 0, 0, 0);
        }
#pragma unroll
        for (int m = 0; m < 2; ++m)
#pragma unroll
            for (int n = 0; n < 3; ++n)
#pragma unroll
                for (int i = 0; i < 4; ++i)
                    xq_d[kw][m * 16 + q * 4 + i][n * 16 + col] = xq[m * 3 + n][i];
        __syncthreads();
#pragma unroll
        for (int e = 0; e < 2; ++e) {
            const int hl = eh2 + e;
            float s0 = 0.f, s1 = 0.f, s2 = 0.f;
#pragma unroll
            for (int c = 0; c < 4; ++c) {
                s0 += xq_d[c][eb][hl];
                s1 += xq_d[c][eb][16 + hl];
                s2 += xq_d[c][eb][32 + hl];
            }
            xq_r[e][0] = s0; xq_r[e][1] = s1; xq_r[e][2] = s2;
        }
        float2 h0 = *(const float2*)(hidden0 + (size_t)ebg * NH + hg0);
        hprev[0] = h0.x; hprev[1] = h0.y;
        st_hB2(hB + (size_t)ebg * NH + hg0, f2bf(h0.x), f2bf(h0.y));   // slot 0
    }
    // prefetch slice 1 (consumed by xq GEMM of t=0)
    {
        const unsigned short* Ax = xbf + (size_t)1 * NH + xrow;
#pragma unroll
        for (int s = 0; s < 8; ++s) {
            xa0[s] = *(const short8*)(Ax + s * 32);
            xa1[s] = *(const short8*)(Ax + xtile1 + s * 32);
        }
    }
    bb_barrier(slots, hc, 1u);

    // ---- recurrent loop ----
    for (int t = 0; t < NT; ++t) {
        // issue ALL hB loads first (LLC latency), then run the hB-independent
        // xq MFMAs while they are in flight, then the hp MFMAs.
        short8 ha0[8], ha1[8];
        {
            const unsigned short* Ah = hB + (size_t)(t & 1) * (NB * NH)
                                          + (size_t)(bb * 32 + col) * NH + koff;
#pragma unroll
            for (int s = 0; s < 8; ++s) {
                ha0[s] = ld_hB16(Ah + s * 32);
                ha1[s] = ld_hB16(Ah + 16 * NH + s * 32);
            }
        }

        // xq = x_{t+1} · w_ih^T from prefetched fragments (no hB dependency)
        f32x4 xq[6];
#pragma unroll
        for (int i = 0; i < 6; ++i) xq[i] = (f32x4){0.f, 0.f, 0.f, 0.f};
        if (t + 1 < NT) {
#pragma unroll
            for (int s = 0; s < 8; ++s) {
                xq[0] = __builtin_amdgcn_mfma_f32_16x16x32_bf16(xa0[s], wf_ih[0][s], xq[0], 0, 0, 0);
                xq[1] = __builtin_amdgcn_mfma_f32_16x16x32_bf16(xa0[s], wf_ih[1][s], xq[1], 0, 0, 0);
                xq[2] = __builtin_amdgcn_mfma_f32_16x16x32_bf16(xa0[s], wf_ih[2][s], xq[2], 0, 0, 0);
                xq[3] = __builtin_amdgcn_mfma_f32_16x16x32_bf16(xa1[s], wf_ih[0][s], xq[3], 0, 0, 0);
                xq[4] = __builtin_amdgcn_mfma_f32_16x16x32_bf16(xa1[s], wf_ih[1][s], xq[4], 0, 0, 0);
                xq[5] = __builtin_amdgcn_mfma_f32_16x16x32_bf16(xa1[s], wf_ih[2][s], xq[5], 0, 0, 0);
            }
        }

        // hp = h_t · w_hh^T (A from the in-flight hB loads, B from regs)
        f32x4 hp[6];
#pragma unroll
        for (int i = 0; i < 6; ++i) hp[i] = (f32x4){0.f, 0.f, 0.f, 0.f};
#pragma unroll
        for (int s = 0; s < 8; ++s) {
            hp[0] = __builtin_amdgcn_mfma_f32_16x16x32_bf16(ha0[s], wf_hh[0][s], hp[0], 0, 0, 0);
            hp[1] = __builtin_amdgcn_mfma_f32_16x16x32_bf16(ha0[s], wf_hh[1][s], hp[1], 0, 0, 0);
            hp[2] = __builtin_amdgcn_mfma_f32_16x16x32_bf16(ha0[s], wf_hh[2][s], hp[2], 0, 0, 0);
            hp[3] = __builtin_amdgcn_mfma_f32_16x16x32_bf16(ha1[s], wf_hh[0][s], hp[3], 0, 0, 0);
            hp[4] = __builtin_amdgcn_mfma_f32_16x16x32_bf16(ha1[s], wf_hh[1][s], hp[4], 0, 0, 0);
            hp[5] = __builtin_amdgcn_mfma_f32_16x16x32_bf16(ha1[s], wf_hh[2][s], hp[5], 0, 0, 0);
        }

        // dump k-split partials
#pragma unroll
        for (int m = 0; m < 2; ++m)
#pragma unroll
            for (int n = 0; n < 3; ++n)
#pragma unroll
                for (int i = 0; i < 4; ++i) {
                    hp_d[kw][m * 16 + q * 4 + i][n * 16 + col] = hp[m * 3 + n][i];
                    xq_d[kw][m * 16 + q * 4 + i][n * 16 + col] = xq[m * 3 + n][i];
                }
        __syncthreads();

        // x prefetch t+2 issued EARLY: HBM latency hides under the epilogue
        if (t + 2 < NT) {
            const unsigned short* Ax = xbf + (size_t)(t + 2) * NH + xrow;
#pragma unroll
            for (int s = 0; s < 8; ++s) {
                xa0[s] = *(const short8*)(Ax + s * 32);
                xa1[s] = *(const short8*)(Ax + xtile1 + s * 32);
            }
        }

        // gates epilogue (all state in registers); stores issued before the
        // xq_r reduction so the hB store latency starts earlier
        float hn2[2];
#pragma unroll
        for (int e = 0; e < 2; ++e) {
            const int hl = eh2 + e;
            float hr = bh_r[e][0], hz = bh_r[e][1], hn = bh_r[e][2];
#pragma unroll
            for (int c = 0; c < 4; ++c) {
                hr += hp_d[c][eb][hl];
                hz += hp_d[c][eb][16 + hl];
                hn += hp_d[c][eb][32 + hl];
            }
            const float r  = sigm_f(xq_r[e][0] + bi_r[e][0] + hr);
            const float z  = sigm_f(xq_r[e][1] + bi_r[e][1] + hz);
            const float nn = tanh_f(xq_r[e][2] + bi_r[e][2] + r * hn);
            const float hv = (1.f - z) * nn + z * hprev[e];
            hprev[e] = hv;
            hn2[e] = hv;
        }
        st_hB2(hB + (size_t)((t + 1) & 1) * (NB * NH) + (size_t)ebg * NH + hg0,
               f2bf(hn2[0]), f2bf(hn2[1]));
        f32x2 o2; o2.x = hn2[0]; o2.y = hn2[1];
        __builtin_nontemporal_store(o2, (f32x2*)(out + ((size_t)ebg * NT + t) * NH + hg0));

#pragma unroll
        for (int e = 0; e < 2; ++e) {
            const int hl = eh2 + e;
            float s0 = 0.f, s1 = 0.f, s2 = 0.f;
#pragma unroll
            for (int c = 0; c < 4; ++c) {
                s0 += xq_d[c][eb][hl];
                s1 += xq_d[c][eb][16 + hl];
                s2 += xq_d[c][eb][32 + hl];
            }
            xq_r[e][0] = s0; xq_r[e][1] = s1; xq_r[e][2] = s2;
        }

        bb_barrier(slots, hc, (unsigned)(t + 2));
    }
}

__global__ __launch_bounds__(256) void zero_cnt_kernel(unsigned* __restrict__ c)
{
    c[threadIdx.x] = 0u;    // 4 groups x 64 slots
}

// ===== old multi-launch fast path (fallback if cooperative launch fails) ====

__device__ __forceinline__ void xq_gemm(
    const unsigned short* xslice, const unsigned short* w_ih,
    int bb, int hc, int col, int koff, f32x4 acc[6])
{
    const unsigned short* Ax = xslice + (size_t)(bb * 32 + col) * (NT * NH) + koff;
    const size_t tile1 = (size_t)16 * NT * NH;
    const unsigned short* W0 = w_ih + (size_t)(0 * NH + hc * 16 + col) * NH + koff;
    const unsigned short* W1 = w_ih + (size_t)(1 * NH + hc * 16 + col) * NH + koff;
    const unsigned short* W2 = w_ih + (size_t)(2 * NH + hc * 16 + col) * NH + koff;
#pragma unroll
    for (int s = 0; s < 8; ++s) {
        short8 a0 = *(const short8*)(Ax + s * 32);
        short8 a1 = *(const short8*)(Ax + tile1 + s * 32);
        short8 b0 = *(const short8*)(W0 + s * 32);
        short8 b1 = *(const short8*)(W1 + s * 32);
        short8 b2 = *(const short8*)(W2 + s * 32);
        acc[0] = __builtin_amdgcn_mfma_f32_16x16x32_bf16(a0, b0, acc[0], 0, 0, 0);
        acc[1] = __builtin_amdgcn_mfma_f32_16x16x32_bf16(a0, b1, acc[1], 0, 0, 0);
        acc[2] = __builtin_amdgcn_mfma_f32_16x16x32_bf16(a0, b2, acc[2], 0, 0, 0);
        acc[3] = __builtin_amdgcn_mfma_f32_16x16x32_bf16(a1, b0, acc[3], 0, 0, 0);
        acc[4] = __builtin_amdgcn_mfma_f32_16x16x32_bf16(a1, b1, acc[4], 0, 0, 0);
        acc[5] = __builtin_amdgcn_mfma_f32_16x16x32_bf16(a1, b2, acc[5], 0, 0, 0);
    }
}

__global__ __launch_bounds__(256) void gru_init_kernel(
    const unsigned short* __restrict__ xbf,
    const float* __restrict__ hidden0,
    const unsigned short* __restrict__ w_ih,
    float* __restrict__ xp, float* __restrict__ hF, unsigned short* __restrict__ hB)
{
    const int tid = threadIdx.x;
    const int kw = tid >> 6, lane = tid & 63, col = lane & 15, q = lane >> 4;
    const int bb = blockIdx.x >> 6, hc = blockIdx.x & 63;
    const int koff = kw * 256 + q * 8;

    __shared__ float xq_d[4][32][49];

    f32x4 acc[6];
#pragma unroll
    for (int i = 0; i < 6; ++i) acc[i] = (f32x4){0.f, 0.f, 0.f, 0.f};
    xq_gemm(xbf, w_ih, bb, hc, col, koff, acc);

#pragma unroll
    for (int m = 0; m < 2; ++m)
#pragma unroll
        for (int n = 0; n < 3; ++n)
#pragma unroll
            for (int i = 0; i < 4; ++i)
                xq_d[kw][m * 16 + q * 4 + i][n * 16 + col] = acc[m * 3 + n][i];
    __syncthreads();

    const int b = tid >> 3, h2 = (tid & 7) * 2, bg = bb * 32 + b;
#pragma unroll
    for (int e = 0; e < 2; ++e) {
        const int hl = h2 + e;
        const int hg = hc * 16 + hl;
        float s0 = 0.f, s1 = 0.f, s2 = 0.f;
#pragma unroll
        for (int c = 0; c < 4; ++c) {
            s0 += xq_d[c][b][hl];
            s1 += xq_d[c][b][16 + hl];
            s2 += xq_d[c][b][32 + hl];
        }
        float* xpd = xp + (size_t)bg * NG;
        xpd[hg]          = s0;
        xpd[NH + hg]     = s1;
        xpd[2 * NH + hg] = s2;
        const float hv = hidden0[(size_t)bg * NH + hg];
        hF[(size_t)bg * NH + hg] = hv;
        hB[(size_t)bg * NH + hg] = f2bf(hv);
    }
}

__global__ __launch_bounds__(256) void gru_step_kernel(
    float* __restrict__ out,
    const unsigned short* __restrict__ xbf,
    const unsigned short* __restrict__ w_ih,
    const unsigned short* __restrict__ w_hh,
    const float* __restrict__ b_ih,
    const float* __restrict__ b_hh,
    float* __restrict__ xp, float* __restrict__ hF, unsigned short* __restrict__ hB,
    int t)
{
    const int tid = threadIdx.x;
    const int kw = tid >> 6, lane = tid & 63, col = lane & 15, q = lane >> 4;
    const int bb = blockIdx.x >> 6, hc = blockIdx.x & 63;
    const int koff = kw * 256 + q * 8;

    __shared__ float hp_d[4][32][49];
    __shared__ float xq_d[4][32][49];

    f32x4 hp[6];
#pragma unroll
    for (int i = 0; i < 6; ++i) hp[i] = (f32x4){0.f, 0.f, 0.f, 0.f};
    {
        const unsigned short* Ah = hB + (size_t)(t & 1) * (NB * NH)
                                      + (size_t)(bb * 32 + col) * NH + koff;
        const unsigned short* W0 = w_hh + (size_t)(0 * NH + hc * 16 + col) * NH + koff;
        const unsigned short* W1 = w_hh + (size_t)(1 * NH + hc * 16 + col) * NH + koff;
        const unsigned short* W2 = w_hh + (size_t)(2 * NH + hc * 16 + col) * NH + koff;
#pragma unroll
        for (int s = 0; s < 8; ++s) {
            short8 a0 = *(const short8*)(Ah + s * 32);
            short8 a1 = *(const short8*)(Ah + 16 * NH + s * 32);
            short8 b0 = *(const short8*)(W0 + s * 32);
            short8 b1 = *(const short8*)(W1 + s * 32);
            short8 b2 = *(const short8*)(W2 + s * 32);
            hp[0] = __builtin_amdgcn_mfma_f32_16x16x32_bf16(a0, b0, hp[0], 0, 0, 0);
            hp[1] = __builtin_amdgcn_mfma_f32_16x16x32_bf16(a0, b1, hp[1], 0, 0, 0);
            hp[2] = __builtin_amdgcn_mfma_f32_16x16x32_bf16(a0, b2, hp[2], 0, 0, 0);
            hp[3] = __builtin_amdgcn_mfma_f32_16x16x32_bf16(a1, b0, hp[3], 0, 0, 0);
            hp[4] = __builtin_amdgcn_mfma_f32_16x16x32_bf16(a1, b1, hp[4], 0, 0, 0);
            hp[5] = __builtin_amdgcn_mfma_f32_16x16x32_bf16(a1, b2, hp[5], 0, 0, 0);
        }
    }

    f32x4 xq[6];
#pragma unroll
    for (int i = 0; i < 6; ++i) xq[i] = (f32x4){0.f, 0.f, 0.f, 0.f};
    if (t + 1 < NT)
        xq_gemm(xbf + (size_t)(t + 1) * NH, w_ih, bb, hc, col, koff, xq);

#pragma unroll
    for (int m = 0; m < 2; ++m)
#pragma unroll
        for (int n = 0; n < 3; ++n)
#pragma unroll
            for (int i = 0; i < 4; ++i) {
                hp_d[kw][m * 16 + q * 4 + i][n * 16 + col] = hp[m * 3 + n][i];
                xq_d[kw][m * 16 + q * 4 + i][n * 16 + col] = xq[m * 3 + n][i];
            }
    __syncthreads();

    const int b = tid >> 3, h2 = (tid & 7) * 2, bg = bb * 32 + b;
#pragma unroll
    for (int e = 0; e < 2; ++e) {
        const int hl = h2 + e;
        const int hg = hc * 16 + hl;

        const float* xps = xp + (size_t)(t & 1) * (NB * NG) + (size_t)bg * NG;
        float xr = xps[hg]          + b_ih[hg];
        float xz = xps[NH + hg]     + b_ih[NH + hg];
        float xn = xps[2 * NH + hg] + b_ih[2 * NH + hg];
        float hr = b_hh[hg];
        float hz = b_hh[NH + hg];
        float hn = b_hh[2 * NH + hg];
#pragma unroll
        for (int c = 0; c < 4; ++c) {
            hr += hp_d[c][b][hl];
            hz += hp_d[c][b][16 + hl];
            hn += hp_d[c][b][32 + hl];
        }
        const float r = sigm_f(xr + hr);
        const float z = sigm_f(xz + hz);
        const float n = tanh_f(xn + r * hn);
        const float hprev = hF[(size_t)(t & 1) * (NB * NH) + (size_t)bg * NH + hg];
        const float hnew  = (1.f - z) * n + z * hprev;

        hF[(size_t)((t + 1) & 1) * (NB * NH) + (size_t)bg * NH + hg] = hnew;
        hB[(size_t)((t + 1) & 1) * (NB * NH) + (size_t)bg * NH + hg] = f2bf(hnew);
        out[((size_t)bg * NT + t) * NH + hg] = hnew;

        if (t + 1 < NT) {
            float s0 = 0.f, s1 = 0.f, s2 = 0.f;
#pragma unroll
            for (int c = 0; c < 4; ++c) {
                s0 += xq_d[c][b][hl];
                s1 += xq_d[c][b][16 + hl];
                s2 += xq_d[c][b][32 + hl];
            }
            float* xpd = xp + (size_t)((t + 1) & 1) * (NB * NG) + (size_t)bg * NG;
            xpd[hg]          = s0;
            xpd[NH + hg]     = s1;
            xpd[2 * NH + hg] = s2;
        }
    }
}

// ===========================================================================
// FALLBACK PATH (fp32 VALU, R5-validated) — 1 MB ws
// ===========================================================================

__global__ __launch_bounds__(256) void xproj_f32_kernel(
    const float* __restrict__ actions, const float* __restrict__ fc_w,
    const float* __restrict__ fc_b, float* __restrict__ xbuf)
{
    const int bt = blockIdx.x, tid = threadIdx.x;
    const float* ap = actions + (size_t)bt * NA;
    float a[8];
#pragma unroll
    for (int i = 0; i < 8; ++i) a[i] = ap[i];
    const int h0 = tid * 4;
    float4 r;
    float* rp = &r.x;
#pragma unroll
    for (int j = 0; j < 4; ++j) {
        const float* wp = fc_w + (size_t)(h0 + j) * NA;
        float acc = fc_b[h0 + j];
#pragma unroll
        for (int i = 0; i < 8; ++i) acc += a[i] * wp[i];
        rp[j] = fmaxf(acc, 0.f);
    }
    *(float4*)(xbuf + (size_t)bt * NH + h0) = r;
}

__global__ __launch_bounds__(512) void hinit_kernel(
    const float* __restrict__ hidden0, float* __restrict__ hF)
{
    const int i = blockIdx.x * 512 + threadIdx.x;
    hF[i] = hidden0[i];
}

__global__ __launch_bounds__(512) void gru_step_valu(
    float* xout, const float* __restrict__ w_ih, const float* __restrict__ w_hh,
    const float* __restrict__ b_ih, const float* __restrict__ b_hh,
    float* __restrict__ hF, int t)
{
    const int tid = threadIdx.x;
    const int b = tid >> 4, hl = tid & 15;
    const int bb = blockIdx.x >> 6, hc = blockIdx.x & 63;
    const int bg = bb * 32 + b, hg = hc * 16 + hl;

    const float* hrow = hF + (size_t)(t & 1) * (NB * NH) + (size_t)bg * NH;
    const float* xrow = xout + ((size_t)bg * NT + t) * NH;
    const float* wrh = w_hh + (size_t)(0 * NH + hg) * NH;
    const float* wzh = w_hh + (size_t)(1 * NH + hg) * NH;
    const float* wnh = w_hh + (size_t)(2 * NH + hg) * NH;
    const float* wrx = w_ih + (size_t)(0 * NH + hg) * NH;
    const float* wzx = w_ih + (size_t)(1 * NH + hg) * NH;
    const float* wnx = w_ih + (size_t)(2 * NH + hg) * NH;

    float hr = 0.f, hz = 0.f, hn = 0.f, xr = 0.f, xz = 0.f, xn = 0.f;
#pragma unroll 4
    for (int k = 0; k < NH; k += 4) {
        float4 hv = *(const float4*)(hrow + k);
        float4 xv = *(const float4*)(xrow + k);
        float4 w;
        w = *(const float4*)(wrh + k); hr += hv.x*w.x + hv.y*w.y + hv.z*w.z + hv.w*w.w;
        w = *(const float4*)(wzh + k); hz += hv.x*w.x + hv.y*w.y + hv.z*w.z + hv.w*w.w;
        w = *(const float4*)(wnh + k); hn += hv.x*w.x + hv.y*w.y + hv.z*w.z + hv.w*w.w;
        w = *(const float4*)(wrx + k); xr += xv.x*w.x + xv.y*w.y + xv.z*w.z + xv.w*w.w;
        w = *(const float4*)(wzx + k); xz += xv.x*w.x + xv.y*w.y + xv.z*w.z + xv.w*w.w;
        w = *(const float4*)(wnx + k); xn += xv.x*w.x + xv.y*w.y + xv.z*w.z + xv.w*w.w;
    }
    const float r = sigm_f(xr + b_ih[hg] + hr + b_hh[hg]);
    const float z = sigm_f(xz + b_ih[NH + hg] + hz + b_hh[NH + hg]);
    const float n = tanh_f(xn + b_ih[2 * NH + hg] + r * (hn + b_hh[2 * NH + hg]));
    const float hprev = hrow[hg];
    const float hnew  = (1.f - z) * n + z * hprev;
    hF[(size_t)((t + 1) & 1) * (NB * NH) + (size_t)bg * NH + hg] = hnew;
    if (t > 0)
        xout[((size_t)bg * NT + (t - 1)) * NH + hg] = hprev;
}

__global__ __launch_bounds__(512) void tail_kernel(
    const float* __restrict__ hF, float* __restrict__ xout)
{
    const int i = blockIdx.x * 512 + threadIdx.x;
    const int b = i >> 10, h = i & (NH - 1);
    xout[((size_t)b * NT + (NT - 1)) * NH + h] = hF[i];
}

// ===========================================================================

extern "C" void kernel_launch(void* const* d_in, const int* in_sizes, int n_in,
                              void* d_out, int out_size, void* d_ws, size_t ws_size,
                              hipStream_t stream)
{
    (void)in_sizes; (void)n_in; (void)out_size;

    const float* actions = (const float*)d_in[0];
    const float* hidden  = (const float*)d_in[1];
    const float* fc_w    = (const float*)d_in[2];
    const float* fc_b    = (const float*)d_in[3];
    const float* w_ih    = (const float*)d_in[4];
    const float* w_hh    = (const float*)d_in[5];
    const float* b_ih    = (const float*)d_in[6];
    const float* b_hh    = (const float*)d_in[7];

    float* outp = (float*)d_out;

    // ws layout (unchanged):
    //   wih_bf 6,291,456 | whh_bf 6,291,456 | xbf 67,108,864
    //   | xp 3,145,728 (persistent path: barrier epoch slots) | hF 1,048,576
    //   | hB 524,288   = 84,410,368 B
    const size_t NEED = 84410368;

    if (ws_size >= NEED) {
        unsigned short* wih_bf = (unsigned short*)d_ws;
        unsigned short* whh_bf = (unsigned short*)((char*)d_ws + 6291456);
        unsigned short* xbf    = (unsigned short*)((char*)d_ws + 12582912);
        unsigned*       slots  = (unsigned*)((char*)d_ws + 79691776);   // reuse xp region
        float*          xp     = (float*)((char*)d_ws + 79691776);
        float*          hF     = (float*)((char*)d_ws + 82837504);
        unsigned short* hB     = (unsigned short*)((char*)d_ws + 83886080);

        wconv_kernel<<<dim3(3072), dim3(256), 0, stream>>>(w_ih, wih_bf, NG * NH);
        wconv_kernel<<<dim3(3072), dim3(256), 0, stream>>>(w_hh, whh_bf, NG * NH);
        xproj_bf16_kernel<<<dim3(NB * NT), dim3(256), 0, stream>>>(actions, fc_w, fc_b, xbf);
        zero_cnt_kernel<<<dim3(1), dim3(256), 0, stream>>>(slots);

        void* kargs[] = { (void*)&outp, (void*)&xbf, (void*)&wih_bf, (void*)&whh_bf,
                          (void*)&b_ih, (void*)&b_hh, (void*)&hidden, (void*)&hB,
                          (void*)&slots };
        hipError_t ce = hipLaunchCooperativeKernel((const void*)gru_persistent,
                                                   dim3(256), dim3(256), kargs, 0, stream);
        if (ce != hipSuccess) {
            // fallback: previous multi-launch fast path
            gru_init_kernel<<<dim3(256), dim3(256), 0, stream>>>(xbf, hidden, wih_bf, xp, hF, hB);
            for (int t = 0; t < NT; ++t)
                gru_step_kernel<<<dim3(256), dim3(256), 0, stream>>>(outp, xbf, wih_bf, whh_bf,
                                                                     b_ih, b_hh, xp, hF, hB, t);
        }
    } else {
        float* hF = (float*)d_ws;   // 1 MB
        xproj_f32_kernel<<<dim3(NB * NT), dim3(256), 0, stream>>>(actions, fc_w, fc_b, outp);
        hinit_kernel<<<dim3(256), dim3(512), 0, stream>>>(hidden, hF);
        for (int t = 0; t < NT; ++t)
            gru_step_valu<<<dim3(256), dim3(512), 0, stream>>>(outp, w_ih, w_hh,
                                                               b_ih, b_hh, hF, t);
        tail_kernel<<<dim3(256), dim3(512), 0, stream>>>(hF, outp);
    }
}

// Round 6
// 2067.376 us; speedup vs baseline: 1.3656x; 1.3656x over previous
//
#include <hip/hip_runtime.h>

typedef __attribute__((ext_vector_type(8))) short short8;   // 8 x bf16 (4 VGPRs)
typedef __attribute__((ext_vector_type(4))) float f32x4;
typedef __attribute__((ext_vector_type(2))) float f32x2;

#define NB 128
#define NT 256
#define NA 8
#define NH 1024
#define NG 3072   // 3*NH

__device__ __forceinline__ unsigned short f2bf(float f) {
    unsigned v;
    __builtin_memcpy(&v, &f, 4);
    v = v + 0x7fffu + ((v >> 16) & 1u);   // round-to-nearest-even
    return (unsigned short)(v >> 16);
}
__device__ __forceinline__ float sigm_f(float u)  { return 1.f / (1.f + __expf(-u)); }
// overflow-safe tanh
__device__ __forceinline__ float tanh_f(float u)  { return 1.f - 2.f / (1.f + __expf(2.f * u)); }

// ===========================================================================
// FAST PATH (MFMA) — needs ~84.4 MB ws
// ===========================================================================

// fp32 -> bf16 pack (weights)
__global__ __launch_bounds__(256) void wconv_kernel(
    const float* __restrict__ src, unsigned short* __restrict__ dst, int n)
{
    for (int i = (blockIdx.x * 256 + threadIdx.x) * 4; i < n; i += gridDim.x * 256 * 4) {
        float4 v = *(const float4*)(src + i);
        ushort4 o;
        o.x = f2bf(v.x); o.y = f2bf(v.y); o.z = f2bf(v.z); o.w = f2bf(v.w);
        *(ushort4*)(dst + i) = o;
    }
}

// x[b,t,h] = relu(actions[b,t,:]·fc_w[h,:] + fc_b[h]) -> bf16 into ws
__global__ __launch_bounds__(256) void xproj_bf16_kernel(
    const float* __restrict__ actions,   // [B,T,A] fp32
    const float* __restrict__ fc_w,      // [H,A]  fp32
    const float* __restrict__ fc_b,      // [H]    fp32
    unsigned short* __restrict__ xbf)    // [B,T,H] bf16 (ws)
{
    const int bt  = blockIdx.x;
    const int tid = threadIdx.x;

    const float* ap = actions + (size_t)bt * NA;
    float a[8];
#pragma unroll
    for (int i = 0; i < 8; ++i) a[i] = ap[i];

    const int h0 = tid * 4;
    unsigned short r[4];
#pragma unroll
    for (int j = 0; j < 4; ++j) {
        const float* wp = fc_w + (size_t)(h0 + j) * NA;
        float acc = fc_b[h0 + j];
#pragma unroll
        for (int i = 0; i < 8; ++i) acc += a[i] * wp[i];
        r[j] = f2bf(fmaxf(acc, 0.f));
    }
    ushort4 pk;
    pk.x = r[0]; pk.y = r[1]; pk.z = r[2]; pk.w = r[3];
    *(ushort4*)(xbf + (size_t)bt * NH + h0) = pk;
}

// ---------------------------------------------------------------------------
// Block tile: (bb 0..3 -> 32 batch rows) x (hc 0..63 -> 16 h outputs = 48
// gate rows). 4 waves k-split K=1024 into 256 each; partials reduced in LDS.
// MFMA 16x16x32 bf16.  A: lane holds A[m=lane&15][k=(lane>>4)*8+j].
//                      B: lane holds B[k=(lane>>4)*8+j][n=lane&15].
//                      D: lane reg i holds D[m=(lane>>4)*4+i][n=lane&15].
// ---------------------------------------------------------------------------

// ======================= persistent cooperative kernel =====================
// R1: acquire/release agent fences emit buffer_inv/wbl2 (L2 wipe) — never.
// R2: single fetch_add counter = same-address RMW serialization at LLC.
// R5: distributed epoch barrier fixed contention, BUT the pre-signal drain
//   (syncthreads => s_waitcnt vmcnt(0)) included the nontemporal out stores
//   (HBM-acked) and the cold x(t+2) HBM prefetch => +1-2 us/step on the
//   critical path. MfmaUtil 6.8% => sync is ~90% of step time.
// R6: SPLIT-PHASE barrier. Signal as soon as hB stores are drained (only
//   16B/thread, LLC-acked). Everything that does not gate other blocks
//   (out store, xq_d->xq_r reduce, x prefetch) moves AFTER the signal,
//   overlapping the inter-block propagation window. Wait happens at the
//   top of the next step, immediately before the hB loads that need it.

__device__ __forceinline__ void bb_wait(const unsigned* slots, unsigned epoch) {
    if (threadIdx.x < 64) {
        for (;;) {
            unsigned v = __hip_atomic_load(slots + (int)threadIdx.x,
                                           __ATOMIC_RELAXED, __HIP_MEMORY_SCOPE_AGENT);
            if (__all((int)(v >= epoch))) break;
            __builtin_amdgcn_s_sleep(1);
        }
    }
    __syncthreads();                 // block-wide order: no hB load before wait
    asm volatile("" ::: "memory");
}

__device__ __forceinline__ void bb_signal(unsigned* slots, int mySlot, unsigned epoch) {
    // __syncthreads emits s_waitcnt vmcnt(0) per wave: hB sc1 stores are
    // LLC-acked (device-visible) before the slot store is issued.
    __syncthreads();
    if (threadIdx.x == 0)
        __hip_atomic_store(slots + mySlot, epoch,
                           __ATOMIC_RELAXED, __HIP_MEMORY_SCOPE_AGENT);
    asm volatile("" ::: "memory");
}

__device__ __forceinline__ short8 ld_hB16(const unsigned short* p) {
    union { unsigned long long u[2]; short8 v; } r;
    r.u[0] = __hip_atomic_load((const unsigned long long*)p,
                               __ATOMIC_RELAXED, __HIP_MEMORY_SCOPE_AGENT);
    r.u[1] = __hip_atomic_load((const unsigned long long*)(p + 4),
                               __ATOMIC_RELAXED, __HIP_MEMORY_SCOPE_AGENT);
    return r.v;
}

__device__ __forceinline__ void st_hB2(unsigned short* p, unsigned short lo, unsigned short hi) {
    unsigned v = (unsigned)lo | ((unsigned)hi << 16);
    __hip_atomic_store((unsigned*)p, v, __ATOMIC_RELAXED, __HIP_MEMORY_SCOPE_AGENT);
}

__global__ __launch_bounds__(256, 1) void gru_persistent(
    float* __restrict__ out,                      // [B,T,H] fp32
    const unsigned short* __restrict__ xbf,       // [B,T,H] bf16
    const unsigned short* __restrict__ wih,      // [3H,H] bf16
    const unsigned short* __restrict__ whh,      // [3H,H] bf16
    const float* __restrict__ b_ih,
    const float* __restrict__ b_hh,
    const float* __restrict__ hidden0,            // [B,H] fp32
    unsigned short* __restrict__ hB,              // [2][B][H] bf16 (LLC-coherent)
    unsigned* __restrict__ slotbase)              // 4 groups x 64 epoch slots
{
    const int tid = threadIdx.x;
    const int kw = tid >> 6, lane = tid & 63, col = lane & 15, q = lane >> 4;
    // XCD-confining swizzle (empirically xcd = bid % 8): bb-group -> 2 XCDs.
    const int bid = (int)blockIdx.x;
    const int bb = (bid & 7) >> 1;
    const int hc = ((bid >> 3) << 1) | (bid & 1);
    const int koff = kw * 256 + q * 8;
    unsigned* slots = slotbase + bb * 64;

    __shared__ float hp_d[4][32][49];
    __shared__ float xq_d[4][32][49];

    // ---- step-invariant weight fragments -> registers (24+24 short8) ----
    short8 wf_hh[3][8], wf_ih[3][8];
#pragma unroll
    for (int g = 0; g < 3; ++g) {
        const unsigned short* Wh = whh + (size_t)(g * NH + hc * 16 + col) * NH + koff;
        const unsigned short* Wi = wih + (size_t)(g * NH + hc * 16 + col) * NH + koff;
#pragma unroll
        for (int s = 0; s < 8; ++s) {
            wf_hh[g][s] = *(const short8*)(Wh + s * 32);
            wf_ih[g][s] = *(const short8*)(Wi + s * 32);
        }
    }

    // ---- epilogue mapping + per-thread persistent state ----
    const int eb = tid >> 3, eh2 = (tid & 7) * 2, ebg = bb * 32 + eb;
    const int hg0 = hc * 16 + eh2;

    float bi_r[2][3], bh_r[2][3];
#pragma unroll
    for (int e = 0; e < 2; ++e)
#pragma unroll
        for (int g = 0; g < 3; ++g) {
            bi_r[e][g] = b_ih[g * NH + hg0 + e];
            bh_r[e][g] = b_hh[g * NH + hg0 + e];
        }

    const size_t xrow   = (size_t)(bb * 32 + col) * (NT * NH) + koff;
    const size_t xtile1 = (size_t)16 * NT * NH;

    // x A-fragment prefetch registers (slice currently needed by xq GEMM)
    short8 xa0[8], xa1[8];
    {
        const unsigned short* Ax = xbf + xrow;    // slice t=0
#pragma unroll
        for (int s = 0; s < 8; ++s) {
            xa0[s] = *(const short8*)(Ax + s * 32);
            xa1[s] = *(const short8*)(Ax + xtile1 + s * 32);
        }
    }

    float xq_r[2][3];   // xp[t] for this thread's 2 outputs (r,z,n)
    float hprev[2];     // h_t for this thread's 2 outputs

    // ---- init: xq(t=0) -> xq_r; h0 -> hprev + hB slot 0 ----
    {
        f32x4 xq[6];
#pragma unroll
        for (int i = 0; i < 6; ++i) xq[i] = (f32x4){0.f, 0.f, 0.f, 0.f};
#pragma unroll
        for (int s = 0; s < 8; ++s) {
            xq[0] = __builtin_amdgcn_mfma_f32_16x16x32_bf16(xa0[s], wf_ih[0][s], xq[0], 0, 0, 0);
            xq[1] = __builtin_amdgcn_mfma_f32_16x16x32_bf16(xa0[s], wf_ih[1][s], xq[1], 0, 0, 0);
            xq[2] = __builtin_amdgcn_mfma_f32_16x16x32_bf16(xa0[s], wf_ih[2][s], xq[2], 0, 0, 0);
            xq[3] = __builtin_amdgcn_mfma_f32_16x16x32_bf16(xa1[s], wf_ih[0][s], xq[3], 0, 0, 0);
            xq[4] = __builtin_amdgcn_mfma_f32_16x16x32_bf16(xa1[s], wf_ih[1][s], xq[4], 0, 0, 0);
            xq[5] = __builtin_amdgcn_mfma_f32_16x16x32_bf16(xa1[s], wf_ih[2][s], xq[5], 0, 0, 0);
        }
#pragma unroll
        for (int m = 0; m < 2; ++m)
#pragma unroll
            for (int n = 0; n < 3; ++n)
#pragma unroll
                for (int i = 0; i < 4; ++i)
                    xq_d[kw][m * 16 + q * 4 + i][n * 16 + col] = xq[m * 3 + n][i];
        __syncthreads();
#pragma unroll
        for (int e = 0; e < 2; ++e) {
            const int hl = eh2 + e;
            float s0 = 0.f, s1 = 0.f, s2 = 0.f;
#pragma unroll
            for (int c = 0; c < 4; ++c) {
                s0 += xq_d[c][eb][hl];
                s1 += xq_d[c][eb][16 + hl];
                s2 += xq_d[c][eb][32 + hl];
            }
            xq_r[e][0] = s0; xq_r[e][1] = s1; xq_r[e][2] = s2;
        }
        float2 h0 = *(const float2*)(hidden0 + (size_t)ebg * NH + hg0);
        hprev[0] = h0.x; hprev[1] = h0.y;
        st_hB2(hB + (size_t)ebg * NH + hg0, f2bf(h0.x), f2bf(h0.y));   // slot 0
    }
    bb_signal(slots, hc, 1u);        // h0 visible; drain covers the hB store
    // shadow of init: prefetch slice 1 (consumed by xq GEMM of t=0)
    {
        const unsigned short* Ax = xbf + (size_t)1 * NH + xrow;
#pragma unroll
        for (int s = 0; s < 8; ++s) {
            xa0[s] = *(const short8*)(Ax + s * 32);
            xa1[s] = *(const short8*)(Ax + xtile1 + s * 32);
        }
    }

    // ---- recurrent loop ----
    for (int t = 0; t < NT; ++t) {
        bb_wait(slots, (unsigned)(t + 1));   // h_t visible everywhere

        // issue ALL hB loads first (LLC latency), then run the hB-independent
        // xq MFMAs while they are in flight, then the hp MFMAs.
        short8 ha0[8], ha1[8];
        {
            const unsigned short* Ah = hB + (size_t)(t & 1) * (NB * NH)
                                          + (size_t)(bb * 32 + col) * NH + koff;
#pragma unroll
            for (int s = 0; s < 8; ++s) {
                ha0[s] = ld_hB16(Ah + s * 32);
                ha1[s] = ld_hB16(Ah + 16 * NH + s * 32);
            }
        }

        // xq = x_{t+1} · w_ih^T from prefetched fragments (no hB dependency)
        f32x4 xq[6];
#pragma unroll
        for (int i = 0; i < 6; ++i) xq[i] = (f32x4){0.f, 0.f, 0.f, 0.f};
        if (t + 1 < NT) {
#pragma unroll
            for (int s = 0; s < 8; ++s) {
                xq[0] = __builtin_amdgcn_mfma_f32_16x16x32_bf16(xa0[s], wf_ih[0][s], xq[0], 0, 0, 0);
                xq[1] = __builtin_amdgcn_mfma_f32_16x16x32_bf16(xa0[s], wf_ih[1][s], xq[1], 0, 0, 0);
                xq[2] = __builtin_amdgcn_mfma_f32_16x16x32_bf16(xa0[s], wf_ih[2][s], xq[2], 0, 0, 0);
                xq[3] = __builtin_amdgcn_mfma_f32_16x16x32_bf16(xa1[s], wf_ih[0][s], xq[3], 0, 0, 0);
                xq[4] = __builtin_amdgcn_mfma_f32_16x16x32_bf16(xa1[s], wf_ih[1][s], xq[4], 0, 0, 0);
                xq[5] = __builtin_amdgcn_mfma_f32_16x16x32_bf16(xa1[s], wf_ih[2][s], xq[5], 0, 0, 0);
            }
        }

        // hp = h_t · w_hh^T (A from the in-flight hB loads, B from regs)
        f32x4 hp[6];
#pragma unroll
        for (int i = 0; i < 6; ++i) hp[i] = (f32x4){0.f, 0.f, 0.f, 0.f};
#pragma unroll
        for (int s = 0; s < 8; ++s) {
            hp[0] = __builtin_amdgcn_mfma_f32_16x16x32_bf16(ha0[s], wf_hh[0][s], hp[0], 0, 0, 0);
            hp[1] = __builtin_amdgcn_mfma_f32_16x16x32_bf16(ha0[s], wf_hh[1][s], hp[1], 0, 0, 0);
            hp[2] = __builtin_amdgcn_mfma_f32_16x16x32_bf16(ha0[s], wf_hh[2][s], hp[2], 0, 0, 0);
            hp[3] = __builtin_amdgcn_mfma_f32_16x16x32_bf16(ha1[s], wf_hh[0][s], hp[3], 0, 0, 0);
            hp[4] = __builtin_amdgcn_mfma_f32_16x16x32_bf16(ha1[s], wf_hh[1][s], hp[4], 0, 0, 0);
            hp[5] = __builtin_amdgcn_mfma_f32_16x16x32_bf16(ha1[s], wf_hh[2][s], hp[5], 0, 0, 0);
        }

        // dump k-split partials
#pragma unroll
        for (int m = 0; m < 2; ++m)
#pragma unroll
            for (int n = 0; n < 3; ++n)
#pragma unroll
                for (int i = 0; i < 4; ++i) {
                    hp_d[kw][m * 16 + q * 4 + i][n * 16 + col] = hp[m * 3 + n][i];
                    xq_d[kw][m * 16 + q * 4 + i][n * 16 + col] = xq[m * 3 + n][i];
                }
        __syncthreads();

        // gates epilogue: ONLY what other blocks wait for (hnew -> hB store)
        float hn2[2];
#pragma unroll
        for (int e = 0; e < 2; ++e) {
            const int hl = eh2 + e;
            float hr = bh_r[e][0], hz = bh_r[e][1], hn = bh_r[e][2];
#pragma unroll
            for (int c = 0; c < 4; ++c) {
                hr += hp_d[c][eb][hl];
                hz += hp_d[c][eb][16 + hl];
                hn += hp_d[c][eb][32 + hl];
            }
            const float r  = sigm_f(xq_r[e][0] + bi_r[e][0] + hr);
            const float z  = sigm_f(xq_r[e][1] + bi_r[e][1] + hz);
            const float nn = tanh_f(xq_r[e][2] + bi_r[e][2] + r * hn);
            const float hv = (1.f - z) * nn + z * hprev[e];
            hprev[e] = hv;
            hn2[e] = hv;
        }
        st_hB2(hB + (size_t)((t + 1) & 1) * (NB * NH) + (size_t)ebg * NH + hg0,
               f2bf(hn2[0]), f2bf(hn2[1]));

        bb_signal(slots, hc, (unsigned)(t + 2));   // drain = hB stores only

        // ---- shadow region: overlaps other blocks' wait window ----
        // out store (regular: L2-acked, drained lazily at next wait)
        f32x2 o2; o2.x = hn2[0]; o2.y = hn2[1];
        *(f32x2*)(out + ((size_t)ebg * NT + t) * NH + hg0) = o2;

        // xq partial reduce for step t+1 (LDS valid until next dump)
        if (t + 1 < NT) {
#pragma unroll
            for (int e = 0; e < 2; ++e) {
                const int hl = eh2 + e;
                float s0 = 0.f, s1 = 0.f, s2 = 0.f;
#pragma unroll
                for (int c = 0; c < 4; ++c) {
                    s0 += xq_d[c][eb][hl];
                    s1 += xq_d[c][eb][16 + hl];
                    s2 += xq_d[c][eb][32 + hl];
                }
                xq_r[e][0] = s0; xq_r[e][1] = s1; xq_r[e][2] = s2;
            }
        }

        // x prefetch t+2 (HBM latency overlaps the next wait)
        if (t + 2 < NT) {
            const unsigned short* Ax = xbf + (size_t)(t + 2) * NH + xrow;
#pragma unroll
            for (int s = 0; s < 8; ++s) {
                xa0[s] = *(const short8*)(Ax + s * 32);
                xa1[s] = *(const short8*)(Ax + xtile1 + s * 32);
            }
        }
    }
}

__global__ __launch_bounds__(256) void zero_cnt_kernel(unsigned* __restrict__ c)
{
    c[threadIdx.x] = 0u;    // 4 groups x 64 slots
}

// ===== old multi-launch fast path (fallback if cooperative launch fails) ====

__device__ __forceinline__ void xq_gemm(
    const unsigned short* xslice, const unsigned short* w_ih,
    int bb, int hc, int col, int koff, f32x4 acc[6])
{
    const unsigned short* Ax = xslice + (size_t)(bb * 32 + col) * (NT * NH) + koff;
    const size_t tile1 = (size_t)16 * NT * NH;
    const unsigned short* W0 = w_ih + (size_t)(0 * NH + hc * 16 + col) * NH + koff;
    const unsigned short* W1 = w_ih + (size_t)(1 * NH + hc * 16 + col) * NH + koff;
    const unsigned short* W2 = w_ih + (size_t)(2 * NH + hc * 16 + col) * NH + koff;
#pragma unroll
    for (int s = 0; s < 8; ++s) {
        short8 a0 = *(const short8*)(Ax + s * 32);
        short8 a1 = *(const short8*)(Ax + tile1 + s * 32);
        short8 b0 = *(const short8*)(W0 + s * 32);
        short8 b1 = *(const short8*)(W1 + s * 32);
        short8 b2 = *(const short8*)(W2 + s * 32);
        acc[0] = __builtin_amdgcn_mfma_f32_16x16x32_bf16(a0, b0, acc[0], 0, 0, 0);
        acc[1] = __builtin_amdgcn_mfma_f32_16x16x32_bf16(a0, b1, acc[1], 0, 0, 0);
        acc[2] = __builtin_amdgcn_mfma_f32_16x16x32_bf16(a0, b2, acc[2], 0, 0, 0);
        acc[3] = __builtin_amdgcn_mfma_f32_16x16x32_bf16(a1, b0, acc[3], 0, 0, 0);
        acc[4] = __builtin_amdgcn_mfma_f32_16x16x32_bf16(a1, b1, acc[4], 0, 0, 0);
        acc[5] = __builtin_amdgcn_mfma_f32_16x16x32_bf16(a1, b2, acc[5], 0, 0, 0);
    }
}

__global__ __launch_bounds__(256) void gru_init_kernel(
    const unsigned short* __restrict__ xbf,
    const float* __restrict__ hidden0,
    const unsigned short* __restrict__ w_ih,
    float* __restrict__ xp, float* __restrict__ hF, unsigned short* __restrict__ hB)
{
    const int tid = threadIdx.x;
    const int kw = tid >> 6, lane = tid & 63, col = lane & 15, q = lane >> 4;
    const int bb = blockIdx.x >> 6, hc = blockIdx.x & 63;
    const int koff = kw * 256 + q * 8;

    __shared__ float xq_d[4][32][49];

    f32x4 acc[6];
#pragma unroll
    for (int i = 0; i < 6; ++i) acc[i] = (f32x4){0.f, 0.f, 0.f, 0.f};
    xq_gemm(xbf, w_ih, bb, hc, col, koff, acc);

#pragma unroll
    for (int m = 0; m < 2; ++m)
#pragma unroll
        for (int n = 0; n < 3; ++n)
#pragma unroll
            for (int i = 0; i < 4; ++i)
                xq_d[kw][m * 16 + q * 4 + i][n * 16 + col] = acc[m * 3 + n][i];
    __syncthreads();

    const int b = tid >> 3, h2 = (tid & 7) * 2, bg = bb * 32 + b;
#pragma unroll
    for (int e = 0; e < 2; ++e) {
        const int hl = h2 + e;
        const int hg = hc * 16 + hl;
        float s0 = 0.f, s1 = 0.f, s2 = 0.f;
#pragma unroll
        for (int c = 0; c < 4; ++c) {
            s0 += xq_d[c][b][hl];
            s1 += xq_d[c][b][16 + hl];
            s2 += xq_d[c][b][32 + hl];
        }
        float* xpd = xp + (size_t)bg * NG;
        xpd[hg]          = s0;
        xpd[NH + hg]     = s1;
        xpd[2 * NH + hg] = s2;
        const float hv = hidden0[(size_t)bg * NH + hg];
        hF[(size_t)bg * NH + hg] = hv;
        hB[(size_t)bg * NH + hg] = f2bf(hv);
    }
}

__global__ __launch_bounds__(256) void gru_step_kernel(
    float* __restrict__ out,
    const unsigned short* __restrict__ xbf,
    const unsigned short* __restrict__ w_ih,
    const unsigned short* __restrict__ w_hh,
    const float* __restrict__ b_ih,
    const float* __restrict__ b_hh,
    float* __restrict__ xp, float* __restrict__ hF, unsigned short* __restrict__ hB,
    int t)
{
    const int tid = threadIdx.x;
    const int kw = tid >> 6, lane = tid & 63, col = lane & 15, q = lane >> 4;
    const int bb = blockIdx.x >> 6, hc = blockIdx.x & 63;
    const int koff = kw * 256 + q * 8;

    __shared__ float hp_d[4][32][49];
    __shared__ float xq_d[4][32][49];

    f32x4 hp[6];
#pragma unroll
    for (int i = 0; i < 6; ++i) hp[i] = (f32x4){0.f, 0.f, 0.f, 0.f};
    {
        const unsigned short* Ah = hB + (size_t)(t & 1) * (NB * NH)
                                      + (size_t)(bb * 32 + col) * NH + koff;
        const unsigned short* W0 = w_hh + (size_t)(0 * NH + hc * 16 + col) * NH + koff;
        const unsigned short* W1 = w_hh + (size_t)(1 * NH + hc * 16 + col) * NH + koff;
        const unsigned short* W2 = w_hh + (size_t)(2 * NH + hc * 16 + col) * NH + koff;
#pragma unroll
        for (int s = 0; s < 8; ++s) {
            short8 a0 = *(const short8*)(Ah + s * 32);
            short8 a1 = *(const short8*)(Ah + 16 * NH + s * 32);
            short8 b0 = *(const short8*)(W0 + s * 32);
            short8 b1 = *(const short8*)(W1 + s * 32);
            short8 b2 = *(const short8*)(W2 + s * 32);
            hp[0] = __builtin_amdgcn_mfma_f32_16x16x32_bf16(a0, b0, hp[0], 0, 0, 0);
            hp[1] = __builtin_amdgcn_mfma_f32_16x16x32_bf16(a0, b1, hp[1], 0, 0, 0);
            hp[2] = __builtin_amdgcn_mfma_f32_16x16x32_bf16(a0, b2, hp[2], 0, 0, 0);
            hp[3] = __builtin_amdgcn_mfma_f32_16x16x32_bf16(a1, b0, hp[3], 0, 0, 0);
            hp[4] = __builtin_amdgcn_mfma_f32_16x16x32_bf16(a1, b1, hp[4], 0, 0, 0);
            hp[5] = __builtin_amdgcn_mfma_f32_16x16x32_bf16(a1, b2, hp[5], 0, 0, 0);
        }
    }

    f32x4 xq[6];
#pragma unroll
    for (int i = 0; i < 6; ++i) xq[i] = (f32x4){0.f, 0.f, 0.f, 0.f};
    if (t + 1 < NT)
        xq_gemm(xbf + (size_t)(t + 1) * NH, w_ih, bb, hc, col, koff, xq);

#pragma unroll
    for (int m = 0; m < 2; ++m)
#pragma unroll
        for (int n = 0; n < 3; ++n)
#pragma unroll
            for (int i = 0; i < 4; ++i) {
                hp_d[kw][m * 16 + q * 4 + i][n * 16 + col] = hp[m * 3 + n][i];
                xq_d[kw][m * 16 + q * 4 + i][n * 16 + col] = xq[m * 3 + n][i];
            }
    __syncthreads();

    const int b = tid >> 3, h2 = (tid & 7) * 2, bg = bb * 32 + b;
#pragma unroll
    for (int e = 0; e < 2; ++e) {
        const int hl = h2 + e;
        const int hg = hc * 16 + hl;

        const float* xps = xp + (size_t)(t & 1) * (NB * NG) + (size_t)bg * NG;
        float xr = xps[hg]          + b_ih[hg];
        float xz = xps[NH + hg]     + b_ih[NH + hg];
        float xn = xps[2 * NH + hg] + b_ih[2 * NH + hg];
        float hr = b_hh[hg];
        float hz = b_hh[NH + hg];
        float hn = b_hh[2 * NH + hg];
#pragma unroll
        for (int c = 0; c < 4; ++c) {
            hr += hp_d[c][b][hl];
            hz += hp_d[c][b][16 + hl];
            hn += hp_d[c][b][32 + hl];
        }
        const float r = sigm_f(xr + hr);
        const float z = sigm_f(xz + hz);
        const float n = tanh_f(xn + r * hn);
        const float hprev = hF[(size_t)(t & 1) * (NB * NH) + (size_t)bg * NH + hg];
        const float hnew  = (1.f - z) * n + z * hprev;

        hF[(size_t)((t + 1) & 1) * (NB * NH) + (size_t)bg * NH + hg] = hnew;
        hB[(size_t)((t + 1) & 1) * (NB * NH) + (size_t)bg * NH + hg] = f2bf(hnew);
        out[((size_t)bg * NT + t) * NH + hg] = hnew;

        if (t + 1 < NT) {
            float s0 = 0.f, s1 = 0.f, s2 = 0.f;
#pragma unroll
            for (int c = 0; c < 4; ++c) {
                s0 += xq_d[c][b][hl];
                s1 += xq_d[c][b][16 + hl];
                s2 += xq_d[c][b][32 + hl];
            }
            float* xpd = xp + (size_t)((t + 1) & 1) * (NB * NG) + (size_t)bg * NG;
            xpd[hg]          = s0;
            xpd[NH + hg]     = s1;
            xpd[2 * NH + hg] = s2;
        }
    }
}

// ===========================================================================
// FALLBACK PATH (fp32 VALU, R5-validated) — 1 MB ws
// ===========================================================================

__global__ __launch_bounds__(256) void xproj_f32_kernel(
    const float* __restrict__ actions, const float* __restrict__ fc_w,
    const float* __restrict__ fc_b, float* __restrict__ xbuf)
{
    const int bt = blockIdx.x, tid = threadIdx.x;
    const float* ap = actions + (size_t)bt * NA;
    float a[8];
#pragma unroll
    for (int i = 0; i < 8; ++i) a[i] = ap[i];
    const int h0 = tid * 4;
    float4 r;
    float* rp = &r.x;
#pragma unroll
    for (int j = 0; j < 4; ++j) {
        const float* wp = fc_w + (size_t)(h0 + j) * NA;
        float acc = fc_b[h0 + j];
#pragma unroll
        for (int i = 0; i < 8; ++i) acc += a[i] * wp[i];
        rp[j] = fmaxf(acc, 0.f);
    }
    *(float4*)(xbuf + (size_t)bt * NH + h0) = r;
}

__global__ __launch_bounds__(512) void hinit_kernel(
    const float* __restrict__ hidden0, float* __restrict__ hF)
{
    const int i = blockIdx.x * 512 + threadIdx.x;
    hF[i] = hidden0[i];
}

__global__ __launch_bounds__(512) void gru_step_valu(
    float* xout, const float* __restrict__ w_ih, const float* __restrict__ w_hh,
    const float* __restrict__ b_ih, const float* __restrict__ b_hh,
    float* __restrict__ hF, int t)
{
    const int tid = threadIdx.x;
    const int b = tid >> 4, hl = tid & 15;
    const int bb = blockIdx.x >> 6, hc = blockIdx.x & 63;
    const int bg = bb * 32 + b, hg = hc * 16 + hl;

    const float* hrow = hF + (size_t)(t & 1) * (NB * NH) + (size_t)bg * NH;
    const float* xrow = xout + ((size_t)bg * NT + t) * NH;
    const float* wrh = w_hh + (size_t)(0 * NH + hg) * NH;
    const float* wzh = w_hh + (size_t)(1 * NH + hg) * NH;
    const float* wnh = w_hh + (size_t)(2 * NH + hg) * NH;
    const float* wrx = w_ih + (size_t)(0 * NH + hg) * NH;
    const float* wzx = w_ih + (size_t)(1 * NH + hg) * NH;
    const float* wnx = w_ih + (size_t)(2 * NH + hg) * NH;

    float hr = 0.f, hz = 0.f, hn = 0.f, xr = 0.f, xz = 0.f, xn = 0.f;
#pragma unroll 4
    for (int k = 0; k < NH; k += 4) {
        float4 hv = *(const float4*)(hrow + k);
        float4 xv = *(const float4*)(xrow + k);
        float4 w;
        w = *(const float4*)(wrh + k); hr += hv.x*w.x + hv.y*w.y + hv.z*w.z + hv.w*w.w;
        w = *(const float4*)(wzh + k); hz += hv.x*w.x + hv.y*w.y + hv.z*w.z + hv.w*w.w;
        w = *(const float4*)(wnh + k); hn += hv.x*w.x + hv.y*w.y + hv.z*w.z + hv.w*w.w;
        w = *(const float4*)(wrx + k); xr += xv.x*w.x + xv.y*w.y + xv.z*w.z + xv.w*w.w;
        w = *(const float4*)(wzx + k); xz += xv.x*w.x + xv.y*w.y + xv.z*w.z + xv.w*w.w;
        w = *(const float4*)(wnx + k); xn += xv.x*w.x + xv.y*w.y + xv.z*w.z + xv.w*w.w;
    }
    const float r = sigm_f(xr + b_ih[hg] + hr + b_hh[hg]);
    const float z = sigm_f(xz + b_ih[NH + hg] + hz + b_hh[NH + hg]);
    const float n = tanh_f(xn + b_ih[2 * NH + hg] + r * (hn + b_hh[2 * NH + hg]));
    const float hprev = hrow[hg];
    const float hnew  = (1.f - z) * n + z * hprev;
    hF[(size_t)((t + 1) & 1) * (NB * NH) + (size_t)bg * NH + hg] = hnew;
    if (t > 0)
        xout[((size_t)bg * NT + (t - 1)) * NH + hg] = hprev;
}

__global__ __launch_bounds__(512) void tail_kernel(
    const float* __restrict__ hF, float* __restrict__ xout)
{
    const int i = blockIdx.x * 512 + threadIdx.x;
    const int b = i >> 10, h = i & (NH - 1);
    xout[((size_t)b * NT + (NT - 1)) * NH + h] = hF[i];
}

// ===========================================================================

extern "C" void kernel_launch(void* const* d_in, const int* in_sizes, int n_in,
                              void* d_out, int out_size, void* d_ws, size_t ws_size,
                              hipStream_t stream)
{
    (void)in_sizes; (void)n_in; (void)out_size;

    const float* actions = (const float*)d_in[0];
    const float* hidden  = (const float*)d_in[1];
    const float* fc_w    = (const float*)d_in[2];
    const float* fc_b    = (const float*)d_in[3];
    const float* w_ih    = (const float*)d_in[4];
    const float* w_hh    = (const float*)d_in[5];
    const float* b_ih    = (const float*)d_in[6];
    const float* b_hh    = (const float*)d_in[7];

    float* outp = (float*)d_out;

    // ws layout (unchanged):
    //   wih_bf 6,291,456 | whh_bf 6,291,456 | xbf 67,108,864
    //   | xp 3,145,728 (persistent path: barrier epoch slots) | hF 1,048,576
    //   | hB 524,288   = 84,410,368 B
    const size_t NEED = 84410368;

    if (ws_size >= NEED) {
        unsigned short* wih_bf = (unsigned short*)d_ws;
        unsigned short* whh_bf = (unsigned short*)((char*)d_ws + 6291456);
        unsigned short* xbf    = (unsigned short*)((char*)d_ws + 12582912);
        unsigned*       slots  = (unsigned*)((char*)d_ws + 79691776);   // reuse xp region
        float*          xp     = (float*)((char*)d_ws + 79691776);
        float*          hF     = (float*)((char*)d_ws + 82837504);
        unsigned short* hB     = (unsigned short*)((char*)d_ws + 83886080);

        wconv_kernel<<<dim3(3072), dim3(256), 0, stream>>>(w_ih, wih_bf, NG * NH);
        wconv_kernel<<<dim3(3072), dim3(256), 0, stream>>>(w_hh, whh_bf, NG * NH);
        xproj_bf16_kernel<<<dim3(NB * NT), dim3(256), 0, stream>>>(actions, fc_w, fc_b, xbf);
        zero_cnt_kernel<<<dim3(1), dim3(256), 0, stream>>>(slots);

        void* kargs[] = { (void*)&outp, (void*)&xbf, (void*)&wih_bf, (void*)&whh_bf,
                          (void*)&b_ih, (void*)&b_hh, (void*)&hidden, (void*)&hB,
                          (void*)&slots };
        hipError_t ce = hipLaunchCooperativeKernel((const void*)gru_persistent,
                                                   dim3(256), dim3(256), kargs, 0, stream);
        if (ce != hipSuccess) {
            // fallback: previous multi-launch fast path
            gru_init_kernel<<<dim3(256), dim3(256), 0, stream>>>(xbf, hidden, wih_bf, xp, hF, hB);
            for (int t = 0; t < NT; ++t)
                gru_step_kernel<<<dim3(256), dim3(256), 0, stream>>>(outp, xbf, wih_bf, whh_bf,
                                                                     b_ih, b_hh, xp, hF, hB, t);
        }
    } else {
        float* hF = (float*)d_ws;   // 1 MB
        xproj_f32_kernel<<<dim3(NB * NT), dim3(256), 0, stream>>>(actions, fc_w, fc_b, outp);
        hinit_kernel<<<dim3(256), dim3(512), 0, stream>>>(hidden, hF);
        for (int t = 0; t < NT; ++t)
            gru_step_valu<<<dim3(256), dim3(512), 0, stream>>>(outp, w_ih, w_hh,
                                                               b_ih, b_hh, hF, t);
        tail_kernel<<<dim3(256), dim3(512), 0, stream>>>(hF, outp);
    }
}